// Round 7
// baseline (82.813 us; speedup 1.0000x reference)
//
#include <hip/hip_runtime.h>

// Inverse 2-level orthonormal Haar DWT with zero details ==
// 4x4 nearest-neighbor upsample scaled by 1/4.
// in : [B=128, C=3, 128, 128] f32 (flat)
// out: [B=128, C=3, 512, 512] f32 (flat)
//
// R6 A/B verdict: plain (L2-allocating) stores beat non-temporal by ~15%
// (L2 stages full 128B lines to HBM, fill-kernel mode; nt's direct 16B
// stream loses the merge window). Structure from R5: block = 1024
// consecutive output float4s, thread t stores at base + t + k*256 —
// every store instruction is 64 lanes x 16 B = 1 KB contiguous (full
// sectors, no RMW amplification), 4 independent stores/thread for ILP.
// Input column w4 = t & 127 constant across k; 4 scalar loads, 256 B/wave
// coalesced, re-reads served by L2/L3 (FETCH ~12 MB << 25 MB input).

typedef float f32x4 __attribute__((ext_vector_type(4)));

__global__ void __launch_bounds__(256) haar_upsample4_kernel(
        const float* __restrict__ z, float* __restrict__ out) {
    const int t    = threadIdx.x;
    const int base = blockIdx.x << 10;        // 1024 float4s per block
    const int w4   = t & 127;                 // input pixel column
    const int r0   = (base >> 7) + (t >> 7);  // j>>7 for k=0

    float v[4];
    #pragma unroll
    for (int k = 0; k < 4; ++k) {
        // j = base + k*256 + t ; rest = j>>7 = r0 + 2k ; w4 = j&127 = t&127
        const int rest = r0 + (k << 1);
        const int h    = rest & 511;          // output row
        const int bc   = rest >> 9;           // b*C + c, < 384
        const int h_in = h >> 2;
        v[k] = z[(bc << 14) + (h_in << 7) + w4] * 0.25f;
    }

    f32x4* o = reinterpret_cast<f32x4*>(out) + base + t;
    #pragma unroll
    for (int k = 0; k < 4; ++k) {
        const f32x4 o4 = {v[k], v[k], v[k], v[k]};
        o[k << 8] = o4;
    }
}

extern "C" void kernel_launch(void* const* d_in, const int* in_sizes, int n_in,
                              void* d_out, int out_size, void* d_ws, size_t ws_size,
                              hipStream_t stream) {
    const float* z = (const float*)d_in[0];
    float* out = (float*)d_out;
    const int total4 = out_size >> 2;        // 8,388,608 float4s
    const int grid = total4 >> 10;           // 8192 blocks (exact)
    haar_upsample4_kernel<<<grid, 256, 0, stream>>>(z, out);
}